// Round 12
// baseline (164.459 us; speedup 1.0000x reference)
//
#include <hip/hip_runtime.h>
#include <math.h>

// ---------------- problem constants ----------------
#define B_TOT 8192
#define KE 400      // 16 nodes * 25 t (ecc K)
#define KR 300      // 12 nodes * 25 t (err K)
#define MEP 416     // ecc K padded to 13*32
#define MRP 320     // err K padded to 10*32

#define ROWS 16     // fused_main: 16 batch rows per block -> 512 blocks

// LDS strides (bf16 elements), padded for bank-conflict avoidance
#define SXE_LD 424
#define SXR_LD 328
#define SEH_LD 72
#define A_BYTES (ROWS * (SXE_LD + SXR_LD + SEH_LD) * 2)   // 26368

// ---------------- workspace layout ----------------
// float offsets: bias PARTIALS (no atomics; fm reduces them)
#define OFF_BE 0                      // [16][256] f32 ecc bias partials
#define OFF_BR 4096                   // [12][256] f32 err bias partials
// ushort offsets (from d_ws base viewed as ushort*), 16B-aligned
#define U_AET 14336                   // AwT_ecc [256][416] bf16  (byte 28672)
#define U_ART (U_AET + 256 * MEP)     // AwT_err [256][320] bf16
#define U_WET (U_ART + 256 * MRP)     // WeT     [64][64]  bf16

typedef __attribute__((ext_vector_type(8))) short short8;
typedef __attribute__((ext_vector_type(4))) float floatx4;

__device__ __forceinline__ float sigmoidf_(float x) { return 1.f / (1.f + __expf(-x)); }
__device__ __forceinline__ float tanhf_(float x) { float e = __expf(2.f * x); return (e - 1.f) / (e + 1.f); }
__device__ __forceinline__ unsigned short f2bf(float x) {
    unsigned u = __float_as_uint(x);
    u += 0x7fffu + ((u >> 16) & 1u);          // round-to-nearest-even
    return (unsigned short)(u >> 16);
}
// async global->LDS, 16B per lane; dest = wave-uniform base + lane*16
__device__ __forceinline__ void gload_lds16(const unsigned short* g, unsigned short* l) {
    __builtin_amdgcn_global_load_lds(
        (const __attribute__((address_space(1))) void*)g,
        (__attribute__((address_space(3))) void*)l, 16, 0, 0);
}

// =====================================================================
// Kernel 1 (merged fold): 765 blocks x 256.  IDENTICAL to the 140.6 us
// build.  Launched 3x this round as a timing instrument (idempotent:
// reads only inputs, writes AwT/partials/WeT deterministically, no
// atomics, never reads ws).  fold_dur = (total - 140.6)/2 - ~1.5us gap.
// =====================================================================
__global__ __launch_bounds__(256) void fold_all2(
    const float* __restrict__ wt_ecc, const float* __restrict__ bt_ecc,
    const float* __restrict__ wt_err, const float* __restrict__ bt_err,
    const float* __restrict__ W0_ecc, const float* __restrict__ W1_ecc, const float* __restrict__ b_ecc,
    const float* __restrict__ W0_err, const float* __restrict__ W1_err, const float* __restrict__ b_err,
    const float* __restrict__ Wp_ecc, const float* __restrict__ bp_ecc,
    const float* __restrict__ Wp_err, const float* __restrict__ bp_err,
    const float* __restrict__ We,
    float* __restrict__ wsf, unsigned short* __restrict__ wsu)
{
    const int blk = blockIdx.x;
    const int tid = threadIdx.x;
    const int cq = tid >> 6;    // 0..3 (c-chunk of 8)
    const int g  = tid & 63;

    __shared__ float red0[4][64];
    __shared__ float red1[4][64];
    __shared__ float sw0[64];
    __shared__ float sw1[64];

    if (blk < MEP + MRP) {
        // ---- XCD-chunked bijective swizzle: same-XCD blocks share v-panels ----
        const int kb = (blk & 7) * 92 + (blk >> 3);   // 736 = 8*92 exactly
        const bool is_err = (kb >= MEP);
        const int k  = is_err ? kb - MEP : kb;
        const int KK = is_err ? KR : KE;
        const int MP = is_err ? MRP : MEP;
        const int nv = is_err ? 12 : 16;
        const float* wt = is_err ? wt_err : wt_ecc;
        const float* W0 = is_err ? W0_err : W0_ecc;
        const float* W1 = is_err ? W1_err : W1_ecc;
        const float* Wp = is_err ? Wp_err : Wp_ecc;
        const int ubase = is_err ? U_ART : U_AET;

        float s = 0.f;
        if (k < KK) {                 // block-uniform branch
            const int v = k / 25, tin = k % 25;
            const int t0 = tin > 0 ? tin - 1 : 0;
            const int t1 = tin < 24 ? tin + 1 : 24;
            float s0 = 0.f, s1 = 0.f;
            #pragma unroll
            for (int c8 = 0; c8 < 8; ++c8) {
                const int c = cq * 8 + c8;
                for (int t = t0; t <= t1; ++t) {
                    const int kk = tin - t + 1;      // 0..2
                    const float w = wt[c * 3 + kk];
                    const int ct = (c * 25 + t) * 64 + g;
                    s0 = fmaf(w, W0[ct], s0);
                    s1 = fmaf(w, W1[ct], s1);
                }
            }
            red0[cq][g] = s0;
            red1[cq][g] = s1;
            __syncthreads();
            if (tid < 64)
                sw0[g] = red0[0][g] + red0[1][g] + red0[2][g] + red0[3][g];
            else if (tid < 128)
                sw1[tid - 64] = red1[0][tid - 64] + red1[1][tid - 64] + red1[2][tid - 64] + red1[3][tid - 64];
            __syncthreads();

            const int vp = (v + 1) % nv;
            const int vm = (v + nv - 1) % nv;
            const int h = tid;
            #pragma unroll 4
            for (int gg = 0; gg < 64; ++gg) {
                s = fmaf(sw0[gg], Wp[(v * 64 + gg) * 256 + h], s);
                s = fmaf(-0.5f * sw1[gg], Wp[(vp * 64 + gg) * 256 + h] + Wp[(vm * 64 + gg) * 256 + h], s);
            }
        }
        wsu[ubase + (size_t)tid * MP + k] = f2bf(s);
    } else if (blk < MEP + MRP + 28) {
        // ---- bias chunk: cvec in-block (redundant, parallel), partial dot ----
        const int cb = blk - (MEP + MRP);
        const bool is_err = (cb >= 16);
        const int i = is_err ? cb - 16 : cb;
        const float* bt = is_err ? bt_err : bt_ecc;
        const float* W0 = is_err ? W0_err : W0_ecc;
        const float* W1 = is_err ? W1_err : W1_ecc;
        const float* bb = is_err ? b_err : b_ecc;
        const float* Wp = is_err ? Wp_err : Wp_ecc;
        const float* bp = is_err ? bp_err : bp_ecc;

        float s = 0.f;
        #pragma unroll
        for (int c8 = 0; c8 < 8; ++c8) {
            const int c = cq * 8 + c8;
            const float btc = bt[c];
            #pragma unroll
            for (int t = 0; t < 25; ++t) {
                const int ct = (c * 25 + t) * 64 + g;
                s = fmaf(btc, W0[ct] - W1[ct], s);
            }
        }
        red0[cq][g] = s;
        __syncthreads();
        if (tid < 64)
            sw0[g] = bb[g] + red0[0][g] + red0[1][g] + red0[2][g] + red0[3][g];
        __syncthreads();

        const int h = tid;
        float p = (i == 0) ? bp[h] : 0.f;
        #pragma unroll 4
        for (int jj = 0; jj < 64; ++jj) {
            const int j = i * 64 + jj;
            p = fmaf(sw0[j & 63], Wp[(size_t)j * 256 + h], p);
        }
        wsf[(is_err ? OFF_BR : OFF_BE) + i * 256 + h] = p;
    } else {
        // ---- WeT[e][d] = We[d][e], bf16 ----
        for (int it = 0; it < 16; ++it) {
            const int idx = it * 256 + tid;
            const int e = idx >> 6, d = idx & 63;
            wsu[U_WET + e * 64 + d] = f2bf(We[d * 64 + e]);
        }
    }
}

// =====================================================================
// Kernel 2 (fused, async B-pipeline): byte-identical to the 140.6 us
// build.  16 rows/block, 4 waves, 3-deep per-wave global_load_lds ring,
// zero barriers in the k-loop, counted vmcnt, both-sides XOR swizzle,
// bias = sum of partial regions.  LDS 73.8 KB -> 2 blocks/CU.
// grid = 512 x 256, bounds(256,2).
// =====================================================================
__global__ __launch_bounds__(256, 2) void fused_main(
    const float* __restrict__ ecc, const float* __restrict__ err, const float* __restrict__ ehr,
    const float* __restrict__ wsf, const unsigned short* __restrict__ wsu,
    const float* __restrict__ Wa, const float* __restrict__ ba,
    const float* __restrict__ be_, const float* __restrict__ Wf2, const float* __restrict__ bf2,
    float* __restrict__ out)
{
    const unsigned short* awt_e = wsu + U_AET;
    const unsigned short* awt_r = wsu + U_ART;
    const unsigned short* wet   = wsu + U_WET;
    const float* biasE = wsf + OFF_BE;
    const float* biasR = wsf + OFF_BR;

    __shared__ __align__(16) char smem[A_BYTES + 3 * 16384];
    unsigned short* sxe = (unsigned short*)smem;          // [16][SXE_LD]
    unsigned short* sxr = sxe + ROWS * SXE_LD;            // [16][SXR_LD]
    unsigned short* seh = sxr + ROWS * SXR_LD;            // [16][SEH_LD]
    unsigned short* bbuf = (unsigned short*)(smem + A_BYTES);  // [3][8192]
    // epilogue scratch overlays sxe (used only after the post-MFMA barrier)
    float* pa_part = (float*)smem;                        // [4][16]
    float* at_arr  = pa_part + 64;                        // [16]
    float* po_part = at_arr + 16;                         // [4][16]

    const int tid = threadIdx.x;
    const int row0 = blockIdx.x * ROWS;
    const int wv = tid >> 6, lane = tid & 63;
    const int lm = lane & 15, lq = lane >> 4;
    const int n0 = wv * 64;

    // ---- per-lane B-staging geometry (pre-swizzled global source) ----
    const int srow = lane >> 2;                              // 0..15
    const int scol = ((lane & 3) ^ ((lane >> 3) & 3)) * 8;   // swizzled 8-elem slot
    const unsigned short* geb = awt_e + (size_t)(n0 + srow) * MEP + scol;
    const unsigned short* grb = awt_r + (size_t)(n0 + srow) * MRP + scol;

    // ---- stage B chunks 0 and 1 (async; drains at the A barrier) ----
    {
        unsigned short* ld0 = bbuf + 0 * 8192 + wv * 2048;
        unsigned short* ld1 = bbuf + 1 * 8192 + wv * 2048;
        #pragma unroll
        for (int j = 0; j < 4; ++j) {
            gload_lds16(geb + (size_t)j * 16 * MEP + 0 * 32, ld0 + j * 512);
            gload_lds16(geb + (size_t)j * 16 * MEP + 1 * 32, ld1 + j * 512);
        }
    }

    // ---- stage X_ecc: 16 rows x 106 quads (real quads < 100) ----
    for (int it = 0; it < 7; ++it) {
        const int f = it * 256 + tid;
        if (f < ROWS * 106) {
            const int r = f / 106, q = f - r * 106;
            float4 v = make_float4(0.f, 0.f, 0.f, 0.f);
            if (q < 100) v = *(const float4*)(ecc + (size_t)(row0 + r) * KE + q * 4);
            const unsigned p0 = (unsigned)f2bf(v.x) | ((unsigned)f2bf(v.y) << 16);
            const unsigned p1 = (unsigned)f2bf(v.z) | ((unsigned)f2bf(v.w) << 16);
            *(uint2*)&sxe[r * SXE_LD + q * 4] = make_uint2(p0, p1);
        }
    }
    // ---- stage X_err: 16 rows x 82 quads (real quads < 75) ----
    for (int it = 0; it < 6; ++it) {
        const int f = it * 256 + tid;
        if (f < ROWS * 82) {
            const int r = f / 82, q = f - r * 82;
            float4 v = make_float4(0.f, 0.f, 0.f, 0.f);
            if (q < 75) v = *(const float4*)(err + (size_t)(row0 + r) * KR + q * 4);
            const unsigned p0 = (unsigned)f2bf(v.x) | ((unsigned)f2bf(v.y) << 16);
            const unsigned p1 = (unsigned)f2bf(v.z) | ((unsigned)f2bf(v.w) << 16);
            *(uint2*)&sxr[r * SXR_LD + q * 4] = make_uint2(p0, p1);
        }
    }
    // ---- stage ehr: 16 rows x 16 quads exactly (one iteration) ----
    {
        const int r = tid >> 4, q = tid & 15;
        const float4 v = *(const float4*)(ehr + (size_t)(row0 + r) * 64 + q * 4);
        const unsigned p0 = (unsigned)f2bf(v.x) | ((unsigned)f2bf(v.y) << 16);
        const unsigned p1 = (unsigned)f2bf(v.z) | ((unsigned)f2bf(v.w) << 16);
        *(uint2*)&seh[r * SEH_LD + q * 4] = make_uint2(p0, p1);
    }
    __syncthreads();   // A visible to all waves; B chunks 0/1 also drained here

    floatx4 accE[4], accR[4], accH;
    accH = (floatx4){0.f, 0.f, 0.f, 0.f};
    #pragma unroll
    for (int nt = 0; nt < 4; ++nt) {
        accE[nt] = (floatx4){0.f, 0.f, 0.f, 0.f};
        accR[nt] = (floatx4){0.f, 0.f, 0.f, 0.f};
    }

    // ---- ehr_p = ehr @ We : wave handles e-slab wv (e = 16*wv + lm) ----
    #pragma unroll
    for (int kc = 0; kc < 2; ++kc) {
        const short8 b = *(const short8*)(wet + (wv * 16 + lm) * 64 + kc * 32 + lq * 8);
        const short8 a = *(const short8*)&seh[lm * SEH_LD + kc * 32 + lq * 8];
        accH = __builtin_amdgcn_mfma_f32_16x16x32_bf16(a, b, accH, 0, 0, 0);
    }

    // ---- main k-loop: 23 chunks (13 ecc + 10 err), barrier-free,
    //      3-deep async B pipeline with counted vmcnt ----
    const int rswz = (lq ^ ((lm >> 1) & 3)) * 8;   // swizzled read slot (ushorts)
    #pragma unroll
    for (int kc = 0; kc < 23; ++kc) {
        if (kc <= 20) {
            // stage chunk kc+2
            const int c = kc + 2;
            unsigned short* ld = bbuf + (size_t)(c % 3) * 8192 + wv * 2048;
            if (c < 13) {
                #pragma unroll
                for (int j = 0; j < 4; ++j)
                    gload_lds16(geb + (size_t)j * 16 * MEP + c * 32, ld + j * 512);
            } else {
                #pragma unroll
                for (int j = 0; j < 4; ++j)
                    gload_lds16(grb + (size_t)j * 16 * MRP + (c - 13) * 32, ld + j * 512);
            }
            asm volatile("s_waitcnt vmcnt(8)" ::: "memory");   // chunk kc landed
        } else if (kc == 21) {
            asm volatile("s_waitcnt vmcnt(4)" ::: "memory");
        } else {
            asm volatile("s_waitcnt vmcnt(0)" ::: "memory");
        }
        __builtin_amdgcn_sched_barrier(0);

        const unsigned short* slab = bbuf + (size_t)(kc % 3) * 8192 + wv * 2048;
        if (kc < 13) {
            const short8 a0 = *(const short8*)&sxe[lm * SXE_LD + kc * 32 + lq * 8];
            #pragma unroll
            for (int nt = 0; nt < 4; ++nt) {
                const short8 b = *(const short8*)(slab + (nt * 16 + lm) * 32 + rswz);
                accE[nt] = __builtin_amdgcn_mfma_f32_16x16x32_bf16(a0, b, accE[nt], 0, 0, 0);
            }
        } else {
            const short8 a0 = *(const short8*)&sxr[lm * SXR_LD + (kc - 13) * 32 + lq * 8];
            #pragma unroll
            for (int nt = 0; nt < 4; ++nt) {
                const short8 b = *(const short8*)(slab + (nt * 16 + lm) * 32 + rswz);
                accR[nt] = __builtin_amdgcn_mfma_f32_16x16x32_bf16(a0, b, accR[nt], 0, 0, 0);
            }
        }
    }

    // ---- per-lane epilogue constants: bias = sum of partial regions ----
    float bE[4] = {0.f, 0.f, 0.f, 0.f}, bR[4] = {0.f, 0.f, 0.f, 0.f};
    float wa[4], wf[4];
    #pragma unroll
    for (int i = 0; i < 16; ++i)
        #pragma unroll
        for (int nt = 0; nt < 4; ++nt)
            bE[nt] += biasE[i * 256 + n0 + nt * 16 + lm];
    #pragma unroll
    for (int i = 0; i < 12; ++i)
        #pragma unroll
        for (int nt = 0; nt < 4; ++nt)
            bR[nt] += biasR[i * 256 + n0 + nt * 16 + lm];
    #pragma unroll
    for (int nt = 0; nt < 4; ++nt) {
        const int h = n0 + nt * 16 + lm;
        wa[nt] = Wa[h]; wf[nt] = Wf2[h];
    }
    const int e_lane = wv * 16 + lm;
    const float eh_be = be_[e_lane];
    const float eh_wf = Wf2[256 + e_lane];

    // ---- pass 1: attention logits, pure register + shfl ----
    float pa_lane[4];
    #pragma unroll
    for (int rg = 0; rg < 4; ++rg) {
        float s = 0.f;
        #pragma unroll
        for (int nt = 0; nt < 4; ++nt) {
            const float ev = accE[nt][rg] + bE[nt];
            const float rv = accR[nt][rg] + bR[nt];
            s = fmaf(tanhf_(ev + rv), wa[nt], s);
        }
        s += __shfl_xor(s, 1, 64); s += __shfl_xor(s, 2, 64);
        s += __shfl_xor(s, 4, 64); s += __shfl_xor(s, 8, 64);
        pa_lane[rg] = s;
    }

    __syncthreads();   // all staging-LDS reads complete; safe to overlay scratch
    if (lm == 0) {
        #pragma unroll
        for (int rg = 0; rg < 4; ++rg)
            pa_part[wv * 16 + lq * 4 + rg] = pa_lane[rg];
    }
    __syncthreads();
    if (tid < 16)
        at_arr[tid] = sigmoidf_(pa_part[tid] + pa_part[16 + tid] + pa_part[32 + tid] + pa_part[48 + tid] + ba[0]);
    __syncthreads();

    // ---- pass 2: fused + EHR dot with Wf2, register + shfl ----
    float po_lane[4];
    #pragma unroll
    for (int rg = 0; rg < 4; ++rg) {
        const int r = lq * 4 + rg;
        const float at = at_arr[r];
        const float om = 1.f - at;
        float s = 0.f;
        #pragma unroll
        for (int nt = 0; nt < 4; ++nt) {
            const float ev = accE[nt][rg] + bE[nt];
            const float rv = accR[nt][rg] + bR[nt];
            s = fmaf(fmaxf(at * ev + om * rv, 0.f), wf[nt], s);
        }
        s = fmaf(fmaxf(accH[rg] + eh_be, 0.f), eh_wf, s);
        s += __shfl_xor(s, 1, 64); s += __shfl_xor(s, 2, 64);
        s += __shfl_xor(s, 4, 64); s += __shfl_xor(s, 8, 64);
        po_lane[rg] = s;
    }
    if (lm == 0) {
        #pragma unroll
        for (int rg = 0; rg < 4; ++rg)
            po_part[wv * 16 + lq * 4 + rg] = po_lane[rg];
    }
    __syncthreads();
    if (tid < 16)
        out[row0 + tid] = sigmoidf_(po_part[tid] + po_part[16 + tid] + po_part[32 + tid] + po_part[48 + tid] + bf2[0]);
}

// =====================================================================
extern "C" void kernel_launch(void* const* d_in, const int* in_sizes, int n_in,
                              void* d_out, int out_size, void* d_ws, size_t ws_size,
                              hipStream_t stream)
{
    (void)in_sizes; (void)n_in; (void)out_size; (void)ws_size;
    const float* ecc    = (const float*)d_in[0];
    const float* err    = (const float*)d_in[1];
    const float* ehr    = (const float*)d_in[2];
    const float* wt_ecc = (const float*)d_in[3];
    const float* bt_ecc = (const float*)d_in[4];
    const float* wt_err = (const float*)d_in[5];
    const float* bt_err = (const float*)d_in[6];
    const float* W0_ecc = (const float*)d_in[7];
    const float* W1_ecc = (const float*)d_in[8];
    const float* b_ecc  = (const float*)d_in[9];
    const float* W0_err = (const float*)d_in[10];
    const float* W1_err = (const float*)d_in[11];
    const float* b_err  = (const float*)d_in[12];
    const float* Wp_ecc = (const float*)d_in[13];
    const float* bp_ecc = (const float*)d_in[14];
    const float* Wp_err = (const float*)d_in[15];
    const float* bp_err = (const float*)d_in[16];
    const float* Wa     = (const float*)d_in[17];
    const float* ba     = (const float*)d_in[18];
    const float* We     = (const float*)d_in[19];
    const float* be     = (const float*)d_in[20];
    const float* Wf2    = (const float*)d_in[21];
    const float* bf2    = (const float*)d_in[22];
    float* wsf = (float*)d_ws;
    unsigned short* wsu = (unsigned short*)d_ws;
    float* out = (float*)d_out;

    // --- timing instrument: fold_all2 launched 3x (idempotent) ---
    // fold_dur = (total_this_round - 140.6) / 2 - ~1.5us gap
    fold_all2<<<dim3(MEP + MRP + 28 + 1), dim3(256), 0, stream>>>(
        wt_ecc, bt_ecc, wt_err, bt_err,
        W0_ecc, W1_ecc, b_ecc, W0_err, W1_err, b_err,
        Wp_ecc, bp_ecc, Wp_err, bp_err, We, wsf, wsu);
    fold_all2<<<dim3(MEP + MRP + 28 + 1), dim3(256), 0, stream>>>(
        wt_ecc, bt_ecc, wt_err, bt_err,
        W0_ecc, W1_ecc, b_ecc, W0_err, W1_err, b_err,
        Wp_ecc, bp_ecc, Wp_err, bp_err, We, wsf, wsu);
    fold_all2<<<dim3(MEP + MRP + 28 + 1), dim3(256), 0, stream>>>(
        wt_ecc, bt_ecc, wt_err, bt_err,
        W0_ecc, W1_ecc, b_ecc, W0_err, W1_err, b_err,
        Wp_ecc, bp_ecc, Wp_err, bp_err, We, wsf, wsu);
    fused_main<<<dim3(B_TOT / ROWS), dim3(256), 0, stream>>>(
        ecc, err, ehr, wsf, wsu, Wa, ba, be, Wf2, bf2, out);
}

// Round 14
// 136.548 us; speedup vs baseline: 1.2044x; 1.2044x over previous
//
#include <hip/hip_runtime.h>
#include <math.h>

// ---------------- problem constants ----------------
#define B_TOT 8192
#define KE 400      // 16 nodes * 25 t (ecc K)
#define KR 300      // 12 nodes * 25 t (err K)
#define MEP 416     // ecc K padded to 13*32
#define MRP 320     // err K padded to 10*32

#define ROWS 32     // fused_main: 32 batch rows per block -> 256 blocks

// LDS strides (bf16 elements), padded for bank-conflict avoidance
#define SXE_LD 424
#define SXR_LD 328
#define SEH_LD 72
#define A_BYTES (ROWS * (SXE_LD + SXR_LD + SEH_LD) * 2)   // 52736

// ---------------- workspace layout ----------------
// float offsets: bias PARTIALS (no atomics; fm reduces them)
#define OFF_BE 0                      // [16][256] f32 ecc bias partials
#define OFF_BR 4096                   // [12][256] f32 err bias partials
// ushort offsets (from d_ws base viewed as ushort*), 16B-aligned
#define U_AET 14336                   // AwT_ecc [256][416] bf16  (byte 28672)
#define U_ART (U_AET + 256 * MEP)     // AwT_err [256][320] bf16
#define U_WET (U_ART + 256 * MRP)     // WeT     [64][64]  bf16

typedef __attribute__((ext_vector_type(8))) short short8;
typedef __attribute__((ext_vector_type(4))) float floatx4;

__device__ __forceinline__ float sigmoidf_(float x) { return 1.f / (1.f + __expf(-x)); }
__device__ __forceinline__ float tanhf_(float x) { float e = __expf(2.f * x); return (e - 1.f) / (e + 1.f); }
__device__ __forceinline__ unsigned short f2bf(float x) {
    unsigned u = __float_as_uint(x);
    u += 0x7fffu + ((u >> 16) & 1u);          // round-to-nearest-even
    return (unsigned short)(u >> 16);
}
// async global->LDS, 16B per lane; dest = wave-uniform base + lane*16
__device__ __forceinline__ void gload_lds16(const unsigned short* g, unsigned short* l) {
    __builtin_amdgcn_global_load_lds(
        (const __attribute__((address_space(1))) void*)g,
        (__attribute__((address_space(3))) void*)l, 16, 0, 0);
}

// =====================================================================
// Kernel 1 (merged fold): 765 blocks x 256.  Byte-identical to the
// 140.6 us build (measured 10.5 us via the R11 3x probe).
// =====================================================================
__global__ __launch_bounds__(256) void fold_all2(
    const float* __restrict__ wt_ecc, const float* __restrict__ bt_ecc,
    const float* __restrict__ wt_err, const float* __restrict__ bt_err,
    const float* __restrict__ W0_ecc, const float* __restrict__ W1_ecc, const float* __restrict__ b_ecc,
    const float* __restrict__ W0_err, const float* __restrict__ W1_err, const float* __restrict__ b_err,
    const float* __restrict__ Wp_ecc, const float* __restrict__ bp_ecc,
    const float* __restrict__ Wp_err, const float* __restrict__ bp_err,
    const float* __restrict__ We,
    float* __restrict__ wsf, unsigned short* __restrict__ wsu)
{
    const int blk = blockIdx.x;
    const int tid = threadIdx.x;
    const int cq = tid >> 6;    // 0..3 (c-chunk of 8)
    const int g  = tid & 63;

    __shared__ float red0[4][64];
    __shared__ float red1[4][64];
    __shared__ float sw0[64];
    __shared__ float sw1[64];

    if (blk < MEP + MRP) {
        // ---- XCD-chunked bijective swizzle: same-XCD blocks share v-panels ----
        const int kb = (blk & 7) * 92 + (blk >> 3);   // 736 = 8*92 exactly
        const bool is_err = (kb >= MEP);
        const int k  = is_err ? kb - MEP : kb;
        const int KK = is_err ? KR : KE;
        const int MP = is_err ? MRP : MEP;
        const int nv = is_err ? 12 : 16;
        const float* wt = is_err ? wt_err : wt_ecc;
        const float* W0 = is_err ? W0_err : W0_ecc;
        const float* W1 = is_err ? W1_err : W1_ecc;
        const float* Wp = is_err ? Wp_err : Wp_ecc;
        const int ubase = is_err ? U_ART : U_AET;

        float s = 0.f;
        if (k < KK) {                 // block-uniform branch
            const int v = k / 25, tin = k % 25;
            const int t0 = tin > 0 ? tin - 1 : 0;
            const int t1 = tin < 24 ? tin + 1 : 24;
            float s0 = 0.f, s1 = 0.f;
            #pragma unroll
            for (int c8 = 0; c8 < 8; ++c8) {
                const int c = cq * 8 + c8;
                for (int t = t0; t <= t1; ++t) {
                    const int kk = tin - t + 1;      // 0..2
                    const float w = wt[c * 3 + kk];
                    const int ct = (c * 25 + t) * 64 + g;
                    s0 = fmaf(w, W0[ct], s0);
                    s1 = fmaf(w, W1[ct], s1);
                }
            }
            red0[cq][g] = s0;
            red1[cq][g] = s1;
            __syncthreads();
            if (tid < 64)
                sw0[g] = red0[0][g] + red0[1][g] + red0[2][g] + red0[3][g];
            else if (tid < 128)
                sw1[tid - 64] = red1[0][tid - 64] + red1[1][tid - 64] + red1[2][tid - 64] + red1[3][tid - 64];
            __syncthreads();

            const int vp = (v + 1) % nv;
            const int vm = (v + nv - 1) % nv;
            const int h = tid;
            #pragma unroll 4
            for (int gg = 0; gg < 64; ++gg) {
                s = fmaf(sw0[gg], Wp[(v * 64 + gg) * 256 + h], s);
                s = fmaf(-0.5f * sw1[gg], Wp[(vp * 64 + gg) * 256 + h] + Wp[(vm * 64 + gg) * 256 + h], s);
            }
        }
        wsu[ubase + (size_t)tid * MP + k] = f2bf(s);
    } else if (blk < MEP + MRP + 28) {
        // ---- bias chunk: cvec in-block (redundant, parallel), partial dot ----
        const int cb = blk - (MEP + MRP);
        const bool is_err = (cb >= 16);
        const int i = is_err ? cb - 16 : cb;
        const float* bt = is_err ? bt_err : bt_ecc;
        const float* W0 = is_err ? W0_err : W0_ecc;
        const float* W1 = is_err ? W1_err : W1_ecc;
        const float* bb = is_err ? b_err : b_ecc;
        const float* Wp = is_err ? Wp_err : Wp_ecc;
        const float* bp = is_err ? bp_err : bp_ecc;

        float s = 0.f;
        #pragma unroll
        for (int c8 = 0; c8 < 8; ++c8) {
            const int c = cq * 8 + c8;
            const float btc = bt[c];
            #pragma unroll
            for (int t = 0; t < 25; ++t) {
                const int ct = (c * 25 + t) * 64 + g;
                s = fmaf(btc, W0[ct] - W1[ct], s);
            }
        }
        red0[cq][g] = s;
        __syncthreads();
        if (tid < 64)
            sw0[g] = bb[g] + red0[0][g] + red0[1][g] + red0[2][g] + red0[3][g];
        __syncthreads();

        const int h = tid;
        float p = (i == 0) ? bp[h] : 0.f;
        #pragma unroll 4
        for (int jj = 0; jj < 64; ++jj) {
            const int j = i * 64 + jj;
            p = fmaf(sw0[j & 63], Wp[(size_t)j * 256 + h], p);
        }
        wsf[(is_err ? OFF_BR : OFF_BE) + i * 256 + h] = p;
    } else {
        // ---- WeT[e][d] = We[d][e], bf16 ----
        for (int it = 0; it < 16; ++it) {
            const int idx = it * 256 + tid;
            const int e = idx >> 6, d = idx & 63;
            wsu[U_WET + e * 64 + d] = f2bf(We[d * 64 + e]);
        }
    }
}

// =====================================================================
// Kernel 2 (fused, v4: ROWS=32, 8 waves, async-B ring): 256 blocks x 512.
//   Each wave owns 32 cols x 32 rows (2 m-tiles): per chunk 4 ds_read
//   b128 feed 8 MFMA (vs 5:4 at ROWS=16), and total L2 B-traffic halves
//   (194 -> 97 MB).  Same barrier-free counted-vmcnt ring (2 gloads per
//   chunk per wave -> vmcnt 4/2/0), same both-sides XOR swizzle.
//   LDS 100.7 KB -> 1 block/CU, 8 waves (2/SIMD).
// =====================================================================
__global__ __launch_bounds__(512, 1) void fused_main(
    const float* __restrict__ ecc, const float* __restrict__ err, const float* __restrict__ ehr,
    const float* __restrict__ wsf, const unsigned short* __restrict__ wsu,
    const float* __restrict__ Wa, const float* __restrict__ ba,
    const float* __restrict__ be_, const float* __restrict__ Wf2, const float* __restrict__ bf2,
    float* __restrict__ out)
{
    const unsigned short* awt_e = wsu + U_AET;
    const unsigned short* awt_r = wsu + U_ART;
    const unsigned short* wet   = wsu + U_WET;
    const float* biasE = wsf + OFF_BE;
    const float* biasR = wsf + OFF_BR;

    __shared__ __align__(16) char smem[A_BYTES + 3 * 16384];
    unsigned short* sxe = (unsigned short*)smem;          // [32][SXE_LD]
    unsigned short* sxr = sxe + ROWS * SXE_LD;            // [32][SXR_LD]
    unsigned short* seh = sxr + ROWS * SXR_LD;            // [32][SEH_LD]
    unsigned short* bbuf = (unsigned short*)(smem + A_BYTES);  // [3][8][1024] ushorts
    // epilogue scratch overlays sxe (used only after the post-MFMA barrier)
    float* pa_part = (float*)smem;                        // [8][32]
    float* at_arr  = pa_part + 256;                       // [32]
    float* po_part = at_arr + 32;                         // [8][32]

    const int tid = threadIdx.x;
    const int row0 = blockIdx.x * ROWS;
    const int wv = tid >> 6, lane = tid & 63;
    const int lm = lane & 15, lq = lane >> 4;
    const int n0 = wv * 32;                               // 8 waves x 32-col slabs

    // ---- per-lane B-staging geometry (pre-swizzled global source) ----
    // instr j covers cols n0 + j*16 + (lane>>2); 16B slot = (lane&3)^swz
    const int srow = lane >> 2;                              // 0..15
    const int scol = ((lane & 3) ^ ((lane >> 3) & 3)) * 8;   // swizzled 8-elem slot
    const unsigned short* geb = awt_e + (size_t)(n0 + srow) * MEP + scol;
    const unsigned short* grb = awt_r + (size_t)(n0 + srow) * MRP + scol;

    // ---- stage B chunks 0 and 1 (async; drains at the A barrier) ----
    #pragma unroll
    for (int c = 0; c < 2; ++c) {
        unsigned short* ld = bbuf + c * 8192 + wv * 1024;
        #pragma unroll
        for (int j = 0; j < 2; ++j)
            gload_lds16(geb + (size_t)j * 16 * MEP + c * 32, ld + j * 512);
    }

    // ---- stage X_ecc: 32 rows x 106 quads (real quads < 100) ----
    for (int it = 0; it < 7; ++it) {
        const int f = it * 512 + tid;
        if (f < ROWS * 106) {
            const int r = f / 106, q = f - r * 106;
            float4 v = make_float4(0.f, 0.f, 0.f, 0.f);
            if (q < 100) v = *(const float4*)(ecc + (size_t)(row0 + r) * KE + q * 4);
            const unsigned p0 = (unsigned)f2bf(v.x) | ((unsigned)f2bf(v.y) << 16);
            const unsigned p1 = (unsigned)f2bf(v.z) | ((unsigned)f2bf(v.w) << 16);
            *(uint2*)&sxe[r * SXE_LD + q * 4] = make_uint2(p0, p1);
        }
    }
    // ---- stage X_err: 32 rows x 82 quads (real quads < 75) ----
    for (int it = 0; it < 6; ++it) {
        const int f = it * 512 + tid;
        if (f < ROWS * 82) {
            const int r = f / 82, q = f - r * 82;
            float4 v = make_float4(0.f, 0.f, 0.f, 0.f);
            if (q < 75) v = *(const float4*)(err + (size_t)(row0 + r) * KR + q * 4);
            const unsigned p0 = (unsigned)f2bf(v.x) | ((unsigned)f2bf(v.y) << 16);
            const unsigned p1 = (unsigned)f2bf(v.z) | ((unsigned)f2bf(v.w) << 16);
            *(uint2*)&sxr[r * SXR_LD + q * 4] = make_uint2(p0, p1);
        }
    }
    // ---- stage ehr: 32 rows x 16 quads exactly (one iteration) ----
    {
        const int r = tid >> 4, q = tid & 15;
        const float4 v = *(const float4*)(ehr + (size_t)(row0 + r) * 64 + q * 4);
        const unsigned p0 = (unsigned)f2bf(v.x) | ((unsigned)f2bf(v.y) << 16);
        const unsigned p1 = (unsigned)f2bf(v.z) | ((unsigned)f2bf(v.w) << 16);
        *(uint2*)&seh[r * SEH_LD + q * 4] = make_uint2(p0, p1);
    }
    __syncthreads();   // A visible; B chunks 0/1 drained by the barrier's vmcnt(0)

    floatx4 accE[2][2], accR[2][2], accH[2];
    #pragma unroll
    for (int mt = 0; mt < 2; ++mt) {
        accH[mt] = (floatx4){0.f, 0.f, 0.f, 0.f};
        #pragma unroll
        for (int nt = 0; nt < 2; ++nt) {
            accE[mt][nt] = (floatx4){0.f, 0.f, 0.f, 0.f};
            accR[mt][nt] = (floatx4){0.f, 0.f, 0.f, 0.f};
        }
    }

    // ---- ehr_p: waves 0..3 handle e-slab wv (e = 16*wv + lm), 2 m-tiles ----
    if (wv < 4) {
        #pragma unroll
        for (int kc = 0; kc < 2; ++kc) {
            const short8 b = *(const short8*)(wet + (wv * 16 + lm) * 64 + kc * 32 + lq * 8);
            #pragma unroll
            for (int mt = 0; mt < 2; ++mt) {
                const short8 a = *(const short8*)&seh[(mt * 16 + lm) * SEH_LD + kc * 32 + lq * 8];
                accH[mt] = __builtin_amdgcn_mfma_f32_16x16x32_bf16(a, b, accH[mt], 0, 0, 0);
            }
        }
    }

    // ---- main k-loop: 23 chunks (13 ecc + 10 err), barrier-free,
    //      3-deep async B ring, 2 gloads/chunk, counted vmcnt 4/2/0 ----
    const int rswz = (lq ^ ((lm >> 1) & 3)) * 8;   // swizzled read slot (ushorts)
    #pragma unroll
    for (int kc = 0; kc < 23; ++kc) {
        if (kc <= 20) {
            const int c = kc + 2;
            unsigned short* ld = bbuf + (size_t)(c % 3) * 8192 + wv * 1024;
            if (c < 13) {
                #pragma unroll
                for (int j = 0; j < 2; ++j)
                    gload_lds16(geb + (size_t)j * 16 * MEP + c * 32, ld + j * 512);
            } else {
                #pragma unroll
                for (int j = 0; j < 2; ++j)
                    gload_lds16(grb + (size_t)j * 16 * MRP + (c - 13) * 32, ld + j * 512);
            }
            asm volatile("s_waitcnt vmcnt(4)" ::: "memory");   // chunk kc landed
        } else if (kc == 21) {
            asm volatile("s_waitcnt vmcnt(2)" ::: "memory");
        } else {
            asm volatile("s_waitcnt vmcnt(0)" ::: "memory");
        }
        __builtin_amdgcn_sched_barrier(0);

        const unsigned short* slab = bbuf + (size_t)(kc % 3) * 8192 + wv * 1024;
        if (kc < 13) {
            const short8 a0 = *(const short8*)&sxe[lm * SXE_LD + kc * 32 + lq * 8];
            const short8 a1 = *(const short8*)&sxe[(16 + lm) * SXE_LD + kc * 32 + lq * 8];
            #pragma unroll
            for (int nt = 0; nt < 2; ++nt) {
                const short8 b = *(const short8*)(slab + (nt * 16 + lm) * 32 + rswz);
                accE[0][nt] = __builtin_amdgcn_mfma_f32_16x16x32_bf16(a0, b, accE[0][nt], 0, 0, 0);
                accE[1][nt] = __builtin_amdgcn_mfma_f32_16x16x32_bf16(a1, b, accE[1][nt], 0, 0, 0);
            }
        } else {
            const short8 a0 = *(const short8*)&sxr[lm * SXR_LD + (kc - 13) * 32 + lq * 8];
            const short8 a1 = *(const short8*)&sxr[(16 + lm) * SXR_LD + (kc - 13) * 32 + lq * 8];
            #pragma unroll
            for (int nt = 0; nt < 2; ++nt) {
                const short8 b = *(const short8*)(slab + (nt * 16 + lm) * 32 + rswz);
                accR[0][nt] = __builtin_amdgcn_mfma_f32_16x16x32_bf16(a0, b, accR[0][nt], 0, 0, 0);
                accR[1][nt] = __builtin_amdgcn_mfma_f32_16x16x32_bf16(a1, b, accR[1][nt], 0, 0, 0);
            }
        }
    }

    // ---- per-lane epilogue constants: bias = sum of partial regions ----
    float bE[2] = {0.f, 0.f}, bR[2] = {0.f, 0.f};
    float wa[2], wf[2];
    #pragma unroll
    for (int i = 0; i < 16; ++i)
        #pragma unroll
        for (int nt = 0; nt < 2; ++nt)
            bE[nt] += biasE[i * 256 + n0 + nt * 16 + lm];
    #pragma unroll
    for (int i = 0; i < 12; ++i)
        #pragma unroll
        for (int nt = 0; nt < 2; ++nt)
            bR[nt] += biasR[i * 256 + n0 + nt * 16 + lm];
    #pragma unroll
    for (int nt = 0; nt < 2; ++nt) {
        const int h = n0 + nt * 16 + lm;
        wa[nt] = Wa[h]; wf[nt] = Wf2[h];
    }
    const int e_lane = (wv & 3) * 16 + lm;
    const float eh_be = be_[e_lane];
    const float eh_wf = Wf2[256 + e_lane];

    // ---- pass 1: attention logits, pure register + shfl ----
    float pa_lane[2][4];
    #pragma unroll
    for (int mt = 0; mt < 2; ++mt)
        #pragma unroll
        for (int rg = 0; rg < 4; ++rg) {
            float s = 0.f;
            #pragma unroll
            for (int nt = 0; nt < 2; ++nt) {
                const float ev = accE[mt][nt][rg] + bE[nt];
                const float rv = accR[mt][nt][rg] + bR[nt];
                s = fmaf(tanhf_(ev + rv), wa[nt], s);
            }
            s += __shfl_xor(s, 1, 64); s += __shfl_xor(s, 2, 64);
            s += __shfl_xor(s, 4, 64); s += __shfl_xor(s, 8, 64);
            pa_lane[mt][rg] = s;
        }

    __syncthreads();   // all staging-LDS reads complete; safe to overlay scratch
    if (lm == 0) {
        #pragma unroll
        for (int mt = 0; mt < 2; ++mt)
            #pragma unroll
            for (int rg = 0; rg < 4; ++rg)
                pa_part[wv * 32 + mt * 16 + lq * 4 + rg] = pa_lane[mt][rg];
    }
    __syncthreads();
    if (tid < 32) {
        float t = ba[0];
        #pragma unroll
        for (int w = 0; w < 8; ++w) t += pa_part[w * 32 + tid];
        at_arr[tid] = sigmoidf_(t);
    }
    __syncthreads();

    // ---- pass 2: fused + EHR dot with Wf2, register + shfl ----
    float po_lane[2][4];
    #pragma unroll
    for (int mt = 0; mt < 2; ++mt)
        #pragma unroll
        for (int rg = 0; rg < 4; ++rg) {
            const int r = mt * 16 + lq * 4 + rg;
            const float at = at_arr[r];
            const float om = 1.f - at;
            float s = 0.f;
            #pragma unroll
            for (int nt = 0; nt < 2; ++nt) {
                const float ev = accE[mt][nt][rg] + bE[nt];
                const float rv = accR[mt][nt][rg] + bR[nt];
                s = fmaf(fmaxf(at * ev + om * rv, 0.f), wf[nt], s);
            }
            if (wv < 4)
                s = fmaf(fmaxf(accH[mt][rg] + eh_be, 0.f), eh_wf, s);
            s += __shfl_xor(s, 1, 64); s += __shfl_xor(s, 2, 64);
            s += __shfl_xor(s, 4, 64); s += __shfl_xor(s, 8, 64);
            po_lane[mt][rg] = s;
        }
    if (lm == 0) {
        #pragma unroll
        for (int mt = 0; mt < 2; ++mt)
            #pragma unroll
            for (int rg = 0; rg < 4; ++rg)
                po_part[wv * 32 + mt * 16 + lq * 4 + rg] = po_lane[mt][rg];
    }
    __syncthreads();
    if (tid < 32) {
        float t = bf2[0];
        #pragma unroll
        for (int w = 0; w < 8; ++w) t += po_part[w * 32 + tid];
        out[row0 + tid] = sigmoidf_(t);
    }
}

// =====================================================================
extern "C" void kernel_launch(void* const* d_in, const int* in_sizes, int n_in,
                              void* d_out, int out_size, void* d_ws, size_t ws_size,
                              hipStream_t stream)
{
    (void)in_sizes; (void)n_in; (void)out_size; (void)ws_size;
    const float* ecc    = (const float*)d_in[0];
    const float* err    = (const float*)d_in[1];
    const float* ehr    = (const float*)d_in[2];
    const float* wt_ecc = (const float*)d_in[3];
    const float* bt_ecc = (const float*)d_in[4];
    const float* wt_err = (const float*)d_in[5];
    const float* bt_err = (const float*)d_in[6];
    const float* W0_ecc = (const float*)d_in[7];
    const float* W1_ecc = (const float*)d_in[8];
    const float* b_ecc  = (const float*)d_in[9];
    const float* W0_err = (const float*)d_in[10];
    const float* W1_err = (const float*)d_in[11];
    const float* b_err  = (const float*)d_in[12];
    const float* Wp_ecc = (const float*)d_in[13];
    const float* bp_ecc = (const float*)d_in[14];
    const float* Wp_err = (const float*)d_in[15];
    const float* bp_err = (const float*)d_in[16];
    const float* Wa     = (const float*)d_in[17];
    const float* ba     = (const float*)d_in[18];
    const float* We     = (const float*)d_in[19];
    const float* be     = (const float*)d_in[20];
    const float* Wf2    = (const float*)d_in[21];
    const float* bf2    = (const float*)d_in[22];
    float* wsf = (float*)d_ws;
    unsigned short* wsu = (unsigned short*)d_ws;
    float* out = (float*)d_out;

    fold_all2<<<dim3(MEP + MRP + 28 + 1), dim3(256), 0, stream>>>(
        wt_ecc, bt_ecc, wt_err, bt_err,
        W0_ecc, W1_ecc, b_ecc, W0_err, W1_err, b_err,
        Wp_ecc, bp_ecc, Wp_err, bp_err, We, wsf, wsu);
    fused_main<<<dim3(B_TOT / ROWS), dim3(512), 0, stream>>>(
        ecc, err, ehr, wsf, wsu, Wa, ba, be, Wf2, bf2, out);
}